// Round 2
// baseline (288.753 us; speedup 1.0000x reference)
//
#include <hip/hip_runtime.h>

// AdaptiveHighPassFilter: fused conv3x3(64->9, zero-pad) + softmax over taps
// + hamming reweight/renorm + CARAFE(3x3, reflect-pad) + residual (2x - lp).
//
// R2 changes vs R1:
//  - LDS tile cut from 88KB (18x18x68) to 49KB (10x18x68): stays under the
//    64KiB/workgroup boundary (suspected cause of the post-timing divergence)
//    and gives 3 blocks/CU instead of 1.
//  - block = 128 threads = one 16x8 tile, 1 thread/pixel, all 64 channels
//    per thread so conv-weight addresses stay wave-uniform -> s_load (SMEM
//    pipe), LDS pipe reserved for the x-tile.
//  - interior-block fast path skips the conv zero-pad validity multiplies
//    (block-uniform branch).

#define TSX 16  // tile width
#define TSY 8   // tile height
#define TPX 18  // tile + halo
#define TPY 10
#define CCH 64  // channels
#define CPAD 68 // padded channel stride in LDS (floats): 272B rows, 16B-aligned
#define IH 128
#define IW 128

__global__ __launch_bounds__(128, 1) void ahpf_kernel(
    const float* __restrict__ x, const float* __restrict__ Wg,
    const float* __restrict__ bias, float* __restrict__ out)
{
    __shared__ __align__(16) float sx[TPY][TPX][CPAD];  // 48,960 B

    const int tid = threadIdx.x;
    const int bz  = blockIdx.z;
    const int ty0 = blockIdx.y * TSY;
    const int tx0 = blockIdx.x * TSX;
    const size_t hw = (size_t)IH * IW;
    const float* xb = x + (size_t)bz * CCH * hw;

    // ---- stage reflect-padded tile: 64ch x 10 x 18 = 11520 elems = 90*128
    for (int i = tid; i < CCH * TPY * TPX; i += 128) {
        int xx = i % TPX;
        int t  = i / TPX;
        int yy = t % TPY;
        int c  = t / TPY;
        int gy = ty0 + yy - 1;
        gy = gy < 0 ? -gy : (gy >= IH ? 2 * IH - 2 - gy : gy);
        int gx = tx0 + xx - 1;
        gx = gx < 0 ? -gx : (gx >= IW ? 2 * IW - 2 - gx : gx);
        sx[yy][xx][c] = xb[(size_t)c * hw + (size_t)gy * IW + gx];
    }
    __syncthreads();

    const int ty = tid >> 4;   // 0..7
    const int tx = tid & 15;   // 0..15
    const int h  = ty0 + ty;
    const int w  = tx0 + tx;

    const bool interior = (blockIdx.x > 0) & (blockIdx.x < IW / TSX - 1) &
                          (blockIdx.y > 0) & (blockIdx.y < IH / TSY - 1);

    // conv zero-padding validity per tap (LDS holds reflect values; the conv
    // must see zeros outside the image)
    float vm[9];
    if (!interior) {
#pragma unroll
        for (int k = 0; k < 9; ++k) {
            int hy = h + k / 3 - 1;
            int wx = w + k % 3 - 1;
            vm[k] = (hy >= 0 && hy < IH && wx >= 0 && wx < IW) ? 1.0f : 0.0f;
        }
    }

    // ---- conv: 9 logits, K = 64ch x 9 taps
    float acc[9];
#pragma unroll
    for (int t = 0; t < 9; ++t) acc[t] = bias[t];

#pragma unroll 4
    for (int g = 0; g < 16; ++g) {      // 4 channels per group
        float4 v[9];
#pragma unroll
        for (int k = 0; k < 9; ++k)
            v[k] = *(const float4*)&sx[ty + k / 3][tx + k % 3][g * 4];
        if (!interior) {
#pragma unroll
            for (int k = 0; k < 9; ++k) {
                v[k].x *= vm[k]; v[k].y *= vm[k];
                v[k].z *= vm[k]; v[k].w *= vm[k];
            }
        }
#pragma unroll
        for (int t = 0; t < 9; ++t) {
            // W layout [t][c][ky][kx] flat: (t*64+c)*9 + k
            const float* wp = Wg + ((size_t)t * CCH + g * 4) * 9;
            float a = acc[t];
#pragma unroll
            for (int k = 0; k < 9; ++k) {
                a = fmaf(wp[k],      v[k].x, a);
                a = fmaf(wp[9 + k],  v[k].y, a);
                a = fmaf(wp[18 + k], v[k].z, a);
                a = fmaf(wp[27 + k], v[k].w, a);
            }
            acc[t] = a;
        }
    }

    // ---- softmax * hamming, renormalized (softmax denom cancels)
    const float h0 = 0.08f;
    const float ham[9] = {h0 * h0, h0, h0 * h0,
                          h0,      1.0f, h0,
                          h0 * h0, h0, h0 * h0};
    float mx = acc[0];
#pragma unroll
    for (int t = 1; t < 9; ++t) mx = fmaxf(mx, acc[t]);
    float mk[9];
    float s = 0.0f;
#pragma unroll
    for (int t = 0; t < 9; ++t) {
        mk[t] = __expf(acc[t] - mx) * ham[t];
        s += mk[t];
    }
    const float inv = 1.0f / s;
#pragma unroll
    for (int t = 0; t < 9; ++t) mk[t] *= inv;

    // ---- carafe + residual: out = 2*x - sum_t mk[t] * x_reflect[t]
    float* ob = out + (size_t)bz * CCH * hw + (size_t)h * IW + w;
#pragma unroll 4
    for (int g = 0; g < 16; ++g) {
        float4 v[9];
#pragma unroll
        for (int k = 0; k < 9; ++k)
            v[k] = *(const float4*)&sx[ty + k / 3][tx + k % 3][g * 4];
        float ox = 2.0f * v[4].x;
        float oy = 2.0f * v[4].y;
        float oz = 2.0f * v[4].z;
        float ow = 2.0f * v[4].w;
#pragma unroll
        for (int t = 0; t < 9; ++t) {
            ox = fmaf(-mk[t], v[t].x, ox);
            oy = fmaf(-mk[t], v[t].y, oy);
            oz = fmaf(-mk[t], v[t].z, oz);
            ow = fmaf(-mk[t], v[t].w, ow);
        }
        ob[(size_t)(4 * g + 0) * hw] = ox;
        ob[(size_t)(4 * g + 1) * hw] = oy;
        ob[(size_t)(4 * g + 2) * hw] = oz;
        ob[(size_t)(4 * g + 3) * hw] = ow;
    }
}

extern "C" void kernel_launch(void* const* d_in, const int* in_sizes, int n_in,
                              void* d_out, int out_size, void* d_ws, size_t ws_size,
                              hipStream_t stream) {
    const float* x    = (const float*)d_in[0];
    const float* Wg   = (const float*)d_in[1];
    const float* bias = (const float*)d_in[2];
    float* out        = (float*)d_out;

    const int B = in_sizes[0] / (CCH * IH * IW);
    dim3 grid(IW / TSX, IH / TSY, B);
    ahpf_kernel<<<grid, dim3(128, 1, 1), 0, stream>>>(x, Wg, bias, out);
}

// Round 3
// 108.837 us; speedup vs baseline: 2.6531x; 2.6531x over previous
//
#include <hip/hip_runtime.h>

// AdaptiveHighPassFilter: conv3x3(64->9, zero-pad) -> softmax(taps) -> hamming
// renorm -> CARAFE(3x3, reflect) -> 2x - lowpass.
//
// R3: conv as MFMA GEMM (logits[9xN] = W[9x576] @ im2col(x)).
//  - Weights live in 18 bf16 A-fragments = 72 VGPRs per thread, loaded ONCE
//    (R2's 230us was s_load weight fetches serializing against ds_read on the
//    shared out-of-order lgkmcnt counter -> full drains; MFMA removes the
//    per-pixel weight traffic entirely).
//  - x staged bf16 in LDS sx[18][18][72shorts]; B-frags via ds_read_b128.
//  - W pre-permuted to frag order in a 10.4KB LDS scratch aliased with the
//    mask buffer (barrier separates the lifetimes).
//  - conv zero-pad vs carafe reflect-pad: LDS holds reflect; border blocks
//    zero the B-fragment for out-of-image (pixel,tap) pairs.
//  - softmax entirely cross-lane (shfl_xor 16/32) in the MFMA C/D layout
//    (col=lane&15=pixel, row=quad*4+reg=tap), mask -> LDS, carafe per-pixel.

typedef __attribute__((ext_vector_type(8))) short short8;
typedef __attribute__((ext_vector_type(4))) float floatx4;

#define IH 128
#define IW 128
#define CCH 64
#define TS 16
#define TP 18
#define CSH 72   // shorts per spatial position in sx (64 used + pad)
#define MPAD 13  // smask row stride in floats (coprime to 32 -> conflict-free)

__device__ __forceinline__ unsigned short f2bf(float f) {
    unsigned u = __float_as_uint(f);
    u += 0x7FFFu + ((u >> 16) & 1u);      // round-to-nearest-even
    return (unsigned short)(u >> 16);
}
__device__ __forceinline__ float bf2f(unsigned short s) {
    return __uint_as_float(((unsigned)s) << 16);
}

__global__ __launch_bounds__(256) void ahpf_kernel(
    const float* __restrict__ x, const float* __restrict__ Wg,
    const float* __restrict__ bias, float* __restrict__ out)
{
    __shared__ __align__(16) unsigned short sx[TP * TP * CSH]; // 46,656 B
    __shared__ __align__(16) unsigned char uni[13312];         // 13,312 B
    unsigned short* wb = (unsigned short*)uni;  // phase 1: W frags [s][m<9][32] bf16
    float* smask       = (float*)uni;           // phase 2: mask [256][MPAD]

    const int tid  = threadIdx.x;
    const int lane = tid & 63;
    const int wv   = tid >> 6;
    const int bz   = blockIdx.z;
    const int ty0  = blockIdx.y * TS;
    const int tx0  = blockIdx.x * TS;
    const size_t hw = (size_t)IH * IW;
    const float* xb = x + (size_t)bz * CCH * hw;

    // ---- stage W -> LDS bf16 in fragment order: wb[(s*9+m)*32 + ko],
    //      k = tap*64 + c, step s covers k=32s..32s+31 (tap=s>>1, chalf=s&1)
    for (int i = tid; i < 18 * 9 * 32; i += 256) {
        int s = i / 288, r = i % 288, m = r / 32, ko = r & 31;
        int tap = s >> 1, c = (s & 1) * 32 + ko;
        wb[i] = f2bf(Wg[m * 576 + c * 9 + tap]);  // W[t][c][ky][kx]
    }

    // ---- stage reflect-padded x tile -> LDS bf16 (18*18 pos x 64 ch)
    for (int i = tid; i < CCH * TP * TP; i += 256) {
        int c = i / (TP * TP), p = i % (TP * TP);
        int yy = p / TP, xx = p % TP;
        int gy = ty0 + yy - 1; gy = gy < 0 ? -gy : (gy >= IH ? 2 * IH - 2 - gy : gy);
        int gx = tx0 + xx - 1; gx = gx < 0 ? -gx : (gx >= IW ? 2 * IW - 2 - gx : gx);
        sx[p * CSH + c] = f2bf(xb[(size_t)c * hw + (size_t)gy * IW + gx]);
    }
    __syncthreads();

    // ---- load A-fragments (weights) into VGPRs, once. A[m=lane&15][k=q*8+j]
    const int fm = lane & 15;  // outch row (9..15 are zero rows)
    const int fq = lane >> 4;  // quad
    short8 afr[18];
#pragma unroll
    for (int s = 0; s < 18; ++s) {
        if (fm < 9)
            afr[s] = *(const short8*)&wb[(s * 9 + fm) * 32 + fq * 8];
        else
            afr[s] = (short8)0;
    }
    float bq[4];
#pragma unroll
    for (int r = 0; r < 4; ++r) {
        int t = fq * 4 + r;
        bq[r] = (t < 9) ? bias[t] : 0.0f;
    }
    __syncthreads();  // wb lifetime ends; region becomes smask

    const bool border = (blockIdx.x == 0) | (blockIdx.x == IW / TS - 1) |
                        (blockIdx.y == 0) | (blockIdx.y == IH / TS - 1);
    const int n = lane & 15;  // B-frag pixel column within the row group

    // ---- conv: wave handles 4 tile rows; per row: 18 B-frag reads + 18 MFMA
    for (int rr = 0; rr < 4; ++rr) {
        const int R = wv * 4 + rr;
        floatx4 acc = {0.f, 0.f, 0.f, 0.f};
#pragma unroll
        for (int s = 0; s < 18; ++s) {
            const int tap = s >> 1;
            const int dy = tap / 3 - 1, dx = tap % 3 - 1;
            const int idx = ((R + 1 + dy) * TP + (n + 1 + dx)) * CSH
                          + (s & 1) * 32 + fq * 8;
            short8 bf = *(const short8*)&sx[idx];
            if (border) {
                int hy = ty0 + R + dy, wx = tx0 + n + dx;
                if (hy < 0 || hy >= IH || wx < 0 || wx >= IW) bf = (short8)0;
            }
            acc = __builtin_amdgcn_mfma_f32_16x16x32_bf16(afr[s], bf, acc, 0, 0, 0);
        }
        // epilogue: lane holds taps t=fq*4+r (r=0..3) of pixel (R, n).
        float a0 = acc[0] + bq[0], a1 = acc[1] + bq[1],
              a2 = acc[2] + bq[2], a3 = acc[3] + bq[3];
        const int nval = (fq < 2) ? 4 : (fq == 2 ? 1 : 0);
        float mx = -1e30f;
        if (nval >= 1) mx = a0;
        if (nval >= 4) { mx = fmaxf(mx, a1); mx = fmaxf(mx, fmaxf(a2, a3)); }
        mx = fmaxf(mx, __shfl_xor(mx, 16));
        mx = fmaxf(mx, __shfl_xor(mx, 32));
        auto hamt = [](int t) {
            float a = (t / 3 == 1) ? 1.f : 0.08f;
            float b = (t % 3 == 1) ? 1.f : 0.08f;
            return a * b;
        };
        float e0 = 0, e1 = 0, e2 = 0, e3 = 0, ssum = 0;
        if (nval >= 1) { e0 = __expf(a0 - mx) * hamt(fq * 4 + 0); ssum += e0; }
        if (nval >= 4) { e1 = __expf(a1 - mx) * hamt(fq * 4 + 1); ssum += e1;
                         e2 = __expf(a2 - mx) * hamt(fq * 4 + 2); ssum += e2;
                         e3 = __expf(a3 - mx) * hamt(fq * 4 + 3); ssum += e3; }
        ssum += __shfl_xor(ssum, 16);
        ssum += __shfl_xor(ssum, 32);
        const float inv = 1.0f / ssum;
        const int pix = R * 16 + n;
        if (nval >= 1) smask[pix * MPAD + fq * 4 + 0] = e0 * inv;
        if (nval >= 4) { smask[pix * MPAD + fq * 4 + 1] = e1 * inv;
                         smask[pix * MPAD + fq * 4 + 2] = e2 * inv;
                         smask[pix * MPAD + fq * 4 + 3] = e3 * inv; }
    }

    // ---- carafe + residual; lane = one pixel of this wave's 4-row strip
    {
        const int pr = lane >> 4, pc = lane & 15;
        const int R = wv * 4 + pr;
        const int h = ty0 + R, w = tx0 + pc;
        float mk[9];
#pragma unroll
        for (int t = 0; t < 9; ++t) mk[t] = smask[(R * 16 + pc) * MPAD + t];
        float* ob = out + (size_t)bz * CCH * hw + (size_t)h * IW + w;
        const int pbase = ((R + 1) * TP + (pc + 1)) * CSH;
#pragma unroll 2
        for (int g = 0; g < 8; ++g) {
            float o[8];
            {   // center tap: o = (2 - mk4) * x
                const short8 v = *(const short8*)&sx[pbase + g * 8];
#pragma unroll
                for (int j = 0; j < 8; ++j)
                    o[j] = (2.0f - mk[4]) * bf2f((unsigned short)v[j]);
            }
#pragma unroll
            for (int t = 0; t < 9; ++t) {
                if (t == 4) continue;
                const int dy = t / 3 - 1, dx = t % 3 - 1;
                const short8 v = *(const short8*)&sx[pbase + (dy * TP + dx) * CSH + g * 8];
#pragma unroll
                for (int j = 0; j < 8; ++j)
                    o[j] = fmaf(-mk[t], bf2f((unsigned short)v[j]), o[j]);
            }
#pragma unroll
            for (int j = 0; j < 8; ++j)
                ob[(size_t)(g * 8 + j) * hw] = o[j];
        }
    }
}

extern "C" void kernel_launch(void* const* d_in, const int* in_sizes, int n_in,
                              void* d_out, int out_size, void* d_ws, size_t ws_size,
                              hipStream_t stream) {
    const float* x    = (const float*)d_in[0];
    const float* Wg   = (const float*)d_in[1];
    const float* bias = (const float*)d_in[2];
    float* out        = (float*)d_out;

    const int B = in_sizes[0] / (CCH * IH * IW);
    dim3 grid(IW / TS, IH / TS, B);
    ahpf_kernel<<<grid, dim3(256, 1, 1), 0, stream>>>(x, Wg, bias, out);
}